// Round 4
// baseline (584.395 us; speedup 1.0000x reference)
//
#include <hip/hip_runtime.h>

typedef unsigned short u16;
typedef __attribute__((ext_vector_type(8))) _Float16 f16x8;
typedef __attribute__((ext_vector_type(4))) float f32x4;

#define N_SP 4096
#define C_CH 512
#define B_SZ 4

__device__ __forceinline__ u16 f2h(float f) {
    union { _Float16 h; u16 u; } x; x.h = (_Float16)f; return x.u;
}
__device__ __forceinline__ float h2f(u16 u) {
    union { u16 u; _Float16 h; } x; x.u = u; return (float)x.h;
}
__device__ __forceinline__ void async_cp16(const void* g, void* l) {
    __builtin_amdgcn_global_load_lds((const __attribute__((address_space(1))) unsigned*)g,
                                     (__attribute__((address_space(3))) unsigned*)l, 16, 0, 0);
}
__device__ __forceinline__ float wave_reduce_sum(float v) {
    #pragma unroll
    for (int off = 32; off; off >>= 1) v += __shfl_xor(v, off, 64);
    return v;
}
__device__ __forceinline__ float wave_reduce_max(float v) {
    #pragma unroll
    for (int off = 32; off; off >>= 1) v = fmaxf(v, __shfl_xor(v, off, 64));
    return v;
}

// ---- transpose+cast raw x to fp16 [b][n][c], accumulate per-channel partial stats via atomics ----
__global__ __launch_bounds__(256) void transpose_cast_stats(
        const float* __restrict__ fc, const float* __restrict__ fs,
        u16* __restrict__ xc, u16* __restrict__ xs,
        float* __restrict__ part_s, float* __restrict__ part_ss) {
    __shared__ float tile[64][65];
    const int t = threadIdx.x;
    const int n0 = blockIdx.x * 64, c0 = blockIdx.y * 64;
    const int z = blockIdx.z;                      // (which<<2)|b == wb
    const int b = z & 3, which = z >> 2;
    const float* src = which ? fs : fc;
    u16* dst = which ? xs : xc;
    const int r = t >> 4, q4 = (t & 15) * 4;
    #pragma unroll
    for (int it = 0; it < 4; ++it) {
        const int row = it * 16 + r;
        float4 v = *(const float4*)(src + ((size_t)b * C_CH + c0 + row) * N_SP + n0 + q4);
        tile[row][q4 + 0] = v.x; tile[row][q4 + 1] = v.y;
        tile[row][q4 + 2] = v.z; tile[row][q4 + 3] = v.w;
    }
    __syncthreads();
    // partial stats: quad (4 threads) per channel row
    {
        const int cr = t >> 2, q = t & 3;
        float s = 0.f, ss = 0.f;
        #pragma unroll
        for (int i = 0; i < 16; ++i) {
            float a = tile[cr][q * 16 + i];
            s += a; ss += a * a;
        }
        s += __shfl_xor(s, 1, 64);  s += __shfl_xor(s, 2, 64);
        ss += __shfl_xor(ss, 1, 64); ss += __shfl_xor(ss, 2, 64);
        if (q == 0) {
            atomicAdd(&part_s[z * 512 + c0 + cr], s);
            atomicAdd(&part_ss[z * 512 + c0 + cr], ss);
        }
    }
    // transposed fp16 write
    #pragma unroll
    for (int it = 0; it < 4; ++it) {
        const int nrow = it * 16 + r;
        ushort4 h4;
        h4.x = f2h(tile[q4 + 0][nrow]);
        h4.y = f2h(tile[q4 + 1][nrow]);
        h4.z = f2h(tile[q4 + 2][nrow]);
        h4.w = f2h(tile[q4 + 3][nrow]);
        *(ushort4*)(dst + ((size_t)b * N_SP + n0 + nrow) * C_CH + c0 + q4) = h4;
    }
}

// ---- finalize stats: mu, rsqrt(var_unbiased+eps) ----
__global__ __launch_bounds__(256) void finalize_stats(const float* __restrict__ part_s,
                                                      const float* __restrict__ part_ss,
                                                      float* __restrict__ mu_a,
                                                      float* __restrict__ rs_a) {
    const int wb = blockIdx.x, t = threadIdx.x;
    #pragma unroll
    for (int h = 0; h < 2; ++h) {
        const int c = wb * 512 + h * 256 + t;
        const float S = part_s[c], SS = part_ss[c];
        const float mean = S * (1.f / N_SP);
        const float var = (SS - S * mean) * (1.f / (N_SP - 1));
        mu_a[c] = mean;
        rs_a[c] = rsqrtf(var + 1e-5f);
    }
}

// ---- in-place fp16 normalize: x̂ = (x - mu[c]) * rs[c] ----
__global__ __launch_bounds__(256) void normalize16(u16* __restrict__ xc, u16* __restrict__ xs,
                                                   const float* __restrict__ mu_a,
                                                   const float* __restrict__ rs_a) {
    const int z = blockIdx.y;                      // wb
    const int b = z & 3, which = z >> 2;
    u16* X = (which ? xs : xc) + (size_t)b * (N_SP * C_CH);
    const size_t e = ((size_t)blockIdx.x * 256 + threadIdx.x) * 8;
    const int c = (int)(e & 511);
    u16 v[8];
    *(uint4*)v = *(const uint4*)(X + e);
    const float4 mu0 = *(const float4*)(mu_a + z * 512 + c);
    const float4 mu1 = *(const float4*)(mu_a + z * 512 + c + 4);
    const float4 rs0 = *(const float4*)(rs_a + z * 512 + c);
    const float4 rs1 = *(const float4*)(rs_a + z * 512 + c + 4);
    const float mu[8] = {mu0.x, mu0.y, mu0.z, mu0.w, mu1.x, mu1.y, mu1.z, mu1.w};
    const float rs[8] = {rs0.x, rs0.y, rs0.z, rs0.w, rs1.x, rs1.y, rs1.z, rs1.w};
    #pragma unroll
    for (int i = 0; i < 8; ++i) v[i] = f2h((h2f(v[i]) - mu[i]) * rs[i]);
    *(uint4*)(X + e) = *(const uint4*)v;
}

// ---- weight cast (+transpose for z<3) fp32 -> fp16 ----
__global__ __launch_bounds__(256) void wtrans(const float* __restrict__ W0, const float* __restrict__ W1,
                                              const float* __restrict__ W2, const float* __restrict__ W3,
                                              u16* __restrict__ D0, u16* __restrict__ D1,
                                              u16* __restrict__ D2, u16* __restrict__ D3) {
    __shared__ float tile[64][65];
    const int t = threadIdx.x, z = blockIdx.z;
    const int n0 = blockIdx.x * 64, c0 = blockIdx.y * 64;   // n0 = src col blk, c0 = src row blk
    const float* W = (z == 0) ? W0 : (z == 1) ? W1 : (z == 2) ? W2 : W3;
    u16* D = (z == 0) ? D0 : (z == 1) ? D1 : (z == 2) ? D2 : D3;
    const int r = t >> 4, q4 = (t & 15) * 4;
    #pragma unroll
    for (int it = 0; it < 4; ++it) {
        const int row = it * 16 + r;
        float4 v = *(const float4*)(W + (size_t)(c0 + row) * 512 + n0 + q4);
        if (z == 3) {
            ushort4 h4 = { f2h(v.x), f2h(v.y), f2h(v.z), f2h(v.w) };
            *(ushort4*)(D + (size_t)(c0 + row) * 512 + n0 + q4) = h4;
        } else {
            tile[row][q4 + 0] = v.x; tile[row][q4 + 1] = v.y;
            tile[row][q4 + 2] = v.z; tile[row][q4 + 3] = v.w;
        }
    }
    __syncthreads();
    if (z == 3) return;
    #pragma unroll
    for (int it = 0; it < 4; ++it) {
        const int nrow = it * 16 + r;
        ushort4 h4;
        h4.x = f2h(tile[q4 + 0][nrow]);
        h4.y = f2h(tile[q4 + 1][nrow]);
        h4.z = f2h(tile[q4 + 2][nrow]);
        h4.w = f2h(tile[q4 + 3][nrow]);
        *(ushort4*)(D + (size_t)(n0 + nrow) * 512 + c0 + q4) = h4;
    }
}

// ---- w_u[d] = sum_o b_c1[o] * W_s1[o][d] ----
__global__ __launch_bounds__(256) void wu_gemv(const float* __restrict__ Ws1,
                                               const float* __restrict__ bc1,
                                               float* __restrict__ w_u) {
    const int d = blockIdx.x * 256 + threadIdx.x;
    float acc = 0.f;
    for (int o = 0; o < 512; ++o) acc += bc1[o] * Ws1[(size_t)o * 512 + d];
    w_u[d] = acc;
}

// ---- bfold0[o] = sum_c W_csc[o][c] * b_s2[c] + b_csc[o] ----
__global__ __launch_bounds__(256) void bfold_gemv(const float* __restrict__ Wcsc,
                                                  const float* __restrict__ bs2,
                                                  const float* __restrict__ bcsc,
                                                  float* __restrict__ bfold0) {
    const int o = blockIdx.x * 4 + (threadIdx.x >> 6), l = threadIdx.x & 63;
    const float4 w0 = *(const float4*)(Wcsc + (size_t)o * 512 + l * 8);
    const float4 w1 = *(const float4*)(Wcsc + (size_t)o * 512 + l * 8 + 4);
    const float4 b0 = *(const float4*)(bs2 + l * 8);
    const float4 b1 = *(const float4*)(bs2 + l * 8 + 4);
    float acc = w0.x * b0.x + w0.y * b0.y + w0.z * b0.z + w0.w * b0.w
              + w1.x * b1.x + w1.y * b1.y + w1.z * b1.z + w1.w * b1.w;
    acc = wave_reduce_sum(acc);
    if (l == 0) bfold0[o] = acc + bcsc[o];
}

// ---- u[b][j] = sum_d w_u[d] * x̂s[b][j][d] ----
__global__ __launch_bounds__(256) void u_big(const u16* __restrict__ xs,
                                             const float* __restrict__ w_u,
                                             float* __restrict__ u) {
    const int b = blockIdx.y, w = threadIdx.x >> 6, l = threadIdx.x & 63;
    const float4 u0 = *(const float4*)(w_u + l * 8);
    const float4 u1 = *(const float4*)(w_u + l * 8 + 4);
    #pragma unroll
    for (int jj = 0; jj < 16; ++jj) {
        const int j = blockIdx.x * 64 + w * 16 + jj;
        const u16* row = xs + ((size_t)b * N_SP + j) * C_CH + l * 8;
        f16x8 x = *(const f16x8*)row;
        float acc = (float)x[0] * u0.x + (float)x[1] * u0.y + (float)x[2] * u0.z + (float)x[3] * u0.w
                  + (float)x[4] * u1.x + (float)x[5] * u1.y + (float)x[6] * u1.z + (float)x[7] * u1.w;
        acc = wave_reduce_sum(acc);
        if (l == 0) u[(size_t)b * N_SP + j] = acc;
    }
}

// ---------------- fp16 MFMA GEMM (bt form): D[m][n] = sum_k A[m][k] * B[n][k] ----------------
enum { OUT_F32 = 0, OUT_F16 = 1 };

template<int OUTMODE, int TM>
__global__ __launch_bounds__(256) void gemm_bt(
    const u16* __restrict__ A, const u16* __restrict__ B,
    float* __restrict__ Df, u16* __restrict__ Dh,
    const float* __restrict__ bias_m, const float* __restrict__ bias_n,
    const float* __restrict__ res,
    int M, int N, int K, int lda, int ldb, int ldd,
    size_t sA, size_t sB, size_t sD, size_t sR, int sBm, int sBn)
{
    constexpr int TN = 128, BK = 32;
    constexpr int FM = TM / 32;
    __shared__ u16 smem[(TM + TN) * BK];
    u16* As = smem;
    u16* Bs = smem + TM * BK;

    const int t = threadIdx.x;
    const int l = t & 63, w = t >> 6;
    const int m0 = blockIdx.y * TM, n0 = blockIdx.x * TN;
    const size_t zb = blockIdx.z;
    const u16* pA = A + zb * sA + (size_t)m0 * lda;
    const u16* pB = B + zb * sB + (size_t)n0 * ldb;

    const int wr = (w & 1) * (TM / 2), wc = (w >> 1) * 64;

    f32x4 acc[FM][4] = {};

    for (int k0 = 0; k0 < K; k0 += BK) {
        #pragma unroll
        for (int it = 0; it < TM / 64; ++it) {
            const int L = it * 256 + t;
            const int row = L >> 2, cb = (L & 3) * 8;
            async_cp16(pA + (size_t)row * lda + k0 + cb, As + L * 8);
        }
        #pragma unroll
        for (int it = 0; it < 2; ++it) {
            const int L = it * 256 + t;
            const int row = L >> 2, cb = (L & 3) * 8;
            async_cp16(pB + (size_t)row * ldb + k0 + cb, Bs + L * 8);
        }
        __syncthreads();
        f16x8 af[FM], bf[4];
        #pragma unroll
        for (int i = 0; i < FM; ++i)
            af[i] = *(const f16x8*)(As + (wr + i * 16 + (l & 15)) * BK + (l >> 4) * 8);
        #pragma unroll
        for (int j = 0; j < 4; ++j)
            bf[j] = *(const f16x8*)(Bs + (wc + j * 16 + (l & 15)) * BK + (l >> 4) * 8);
        #pragma unroll
        for (int i = 0; i < FM; ++i)
            #pragma unroll
            for (int j = 0; j < 4; ++j)
                acc[i][j] = __builtin_amdgcn_mfma_f32_16x16x32_f16(af[i], bf[j], acc[i][j], 0, 0, 0);
        __syncthreads();
    }

    const int em = m0 + wr + (l >> 4) * 4;
    const int en = n0 + wc + (l & 15);
    u16* pDh = (OUTMODE == OUT_F16) ? (Dh + zb * sD) : nullptr;
    float* pDf = (OUTMODE == OUT_F32) ? (Df + zb * sD) : nullptr;
    #pragma unroll
    for (int i = 0; i < FM; ++i) {
        #pragma unroll
        for (int j = 0; j < 4; ++j) {
            const int nn = en + j * 16;
            const float bn = bias_n ? bias_n[(size_t)sBn * zb + nn] : 0.f;
            #pragma unroll
            for (int r = 0; r < 4; ++r) {
                const int mm = em + i * 16 + r;
                float v = acc[i][j][r] + bn;
                if (bias_m) v += bias_m[(size_t)sBm * zb + mm];
                const size_t off = (size_t)mm * ldd + nn;
                if (OUTMODE == OUT_F32) {
                    if (res) v += res[zb * sR + off];
                    pDf[off] = v;
                } else {
                    pDh[off] = f2h(v);
                }
            }
        }
    }
}

// ---------------- softmax row-wise, fp16 in-place ----------------
__global__ __launch_bounds__(256) void softmax_kernel(u16* __restrict__ Sbase, size_t sS) {
    u16* row = Sbase + blockIdx.y * sS + (size_t)blockIdx.x * N_SP;
    const int t = threadIdx.x;
    u16 raw[16];
    *(uint4*)(raw + 0) = *(const uint4*)(row + t * 16);
    *(uint4*)(raw + 8) = *(const uint4*)(row + t * 16 + 8);
    float v[16];
    float mx = -1e30f;
    #pragma unroll
    for (int i = 0; i < 16; ++i) { v[i] = h2f(raw[i]); mx = fmaxf(mx, v[i]); }
    mx = wave_reduce_max(mx);
    __shared__ float red[4];
    const int wave = t >> 6;
    if ((t & 63) == 0) red[wave] = mx;
    __syncthreads();
    mx = fmaxf(fmaxf(red[0], red[1]), fmaxf(red[2], red[3]));
    float sum = 0.f;
    #pragma unroll
    for (int i = 0; i < 16; ++i) { v[i] = __expf(v[i] - mx); sum += v[i]; }
    sum = wave_reduce_sum(sum);
    __syncthreads();
    if ((t & 63) == 0) red[wave] = sum;
    __syncthreads();
    const float inv = 1.f / (red[0] + red[1] + red[2] + red[3]);
    #pragma unroll
    for (int i = 0; i < 16; ++i) raw[i] = f2h(v[i] * inv);
    *(uint4*)(row + t * 16)     = *(const uint4*)(raw + 0);
    *(uint4*)(row + t * 16 + 8) = *(const uint4*)(raw + 8);
}

extern "C" void kernel_launch(void* const* d_in, const int* in_sizes, int n_in,
                              void* d_out, int out_size, void* d_ws, size_t ws_size,
                              hipStream_t stream) {
    const float* f_c   = (const float*)d_in[0];
    const float* f_s   = (const float*)d_in[1];
    const float* W_c1  = (const float*)d_in[2];
    const float* b_c1  = (const float*)d_in[3];
    const float* W_s1  = (const float*)d_in[4];
    const float* b_s1  = (const float*)d_in[5]; (void)b_s1;  // b_s1: only enters via softmax-invariant terms & w_u? (w_u uses b_c1·W_s1; b_s1 terms are row-constant → dropped)
    const float* W_s2  = (const float*)d_in[6];
    const float* b_s2  = (const float*)d_in[7];
    const float* W_csc = (const float*)d_in[8];
    const float* b_csc = (const float*)d_in[9];

    const size_t PB = (size_t)N_SP * C_CH;      // 2M elems per batch plane
    const size_t M1 = 1024 * 1024;
    const size_t SSTR = 16 * M1;                // S buffer stride (u16 elems)

    u16* ws   = (u16*)d_ws;
    u16* Xc   = ws;                 // 16 MB, [b][n][c] fp16 (normalized in place)
    u16* Xs   = ws + 8 * M1;        // 16 MB
    u16* q_   = ws + 16 * M1;       // 16 MB  q'[b][i][d]
    u16* hc   = ws + 24 * M1;       // 16 MB  hc[b][o][j]
    u16* S0   = ws + 32 * M1;       // 32 MB  (group S buffers: S0, S0+SSTR)
    u16* Wc1T = ws + 64 * M1;       // 512 KB each fp16
    u16* Ws1T = Wc1T + 262144;
    u16* Ws2T = Ws1T + 262144;
    u16* Wcs16= Ws2T + 262144;
    u16* WqT  = ws + 65 * M1;       // WqT[d][a] fp16
    u16* Wf16 = WqT + 262144;       // Wfold[o][k] fp16
    float* f32b = (float*)(ws + 66 * M1);
    float* part_s  = f32b;          // 4096
    float* part_ss = f32b + 4096;
    float* mu_a    = f32b + 8192;
    float* rs_a    = f32b + 12288;
    float* w_u     = f32b + 16384;  // 512
    float* bfold0  = f32b + 16896;  // 512
    float* u_      = f32b + 17408;  // 4*4096

    hipMemsetAsync(part_s, 0, 2 * 4096 * sizeof(float), stream);

    transpose_cast_stats<<<dim3(64, 8, 8), 256, 0, stream>>>(f_c, f_s, Xc, Xs, part_s, part_ss);
    finalize_stats<<<8, 256, 0, stream>>>(part_s, part_ss, mu_a, rs_a);
    normalize16<<<dim3(1024, 8), 256, 0, stream>>>(Xc, Xs, mu_a, rs_a);

    wtrans<<<dim3(8, 8, 4), 256, 0, stream>>>(W_c1, W_s1, W_s2, W_csc, Wc1T, Ws1T, Ws2T, Wcs16);
    wu_gemv<<<2, 256, 0, stream>>>(W_s1, b_c1, w_u);
    bfold_gemv<<<128, 256, 0, stream>>>(W_csc, b_s2, b_csc, bfold0);

    // WqT[d][a] = sum_o W_s1[o][d] W_c1[o][a]
    gemm_bt<OUT_F16, 128><<<dim3(4, 4, 1), 256, 0, stream>>>(
        Ws1T, Wc1T, nullptr, WqT, nullptr, nullptr, nullptr,
        512, 512, 512, 512, 512, 512, 0, 0, 0, 0, 0, 0);
    // Wfold[o][k] = sum_c W_csc[o][c] W_s2[c][k]
    gemm_bt<OUT_F16, 128><<<dim3(4, 4, 1), 256, 0, stream>>>(
        Wcs16, Ws2T, nullptr, Wf16, nullptr, nullptr, nullptr,
        512, 512, 512, 512, 512, 512, 0, 0, 0, 0, 0, 0);

    // q'[b][i][d] = sum_a x̂c[b][i][a] WqT[d][a]
    gemm_bt<OUT_F16, 128><<<dim3(4, 32, B_SZ), 256, 0, stream>>>(
        Xc, WqT, nullptr, q_, nullptr, nullptr, nullptr,
        N_SP, C_CH, C_CH, C_CH, C_CH, C_CH, PB, 0, PB, 0, 0, 0);
    // hc[b][o][j] = sum_k Wfold[o][k] x̂s[b][j][k] + bfold0[o]
    gemm_bt<OUT_F16, 128><<<dim3(32, 4, B_SZ), 256, 0, stream>>>(
        Wf16, Xs, nullptr, hc, bfold0, nullptr, nullptr,
        C_CH, N_SP, C_CH, C_CH, C_CH, N_SP, 0, PB, PB, 0, 0, 0);
    // u[b][j]
    u_big<<<dim3(64, B_SZ), 256, 0, stream>>>(Xs, w_u, u_);

    for (int g = 0; g < 2; ++g) {
        // S[i][j] = sum_d q'[i][d] x̂s[j][d] + u[j]
        gemm_bt<OUT_F16, 128><<<dim3(32, 32, 2), 256, 0, stream>>>(
            q_ + g * 2 * PB, Xs + g * 2 * PB, nullptr, S0, nullptr, u_ + g * 2 * N_SP, nullptr,
            N_SP, N_SP, C_CH, C_CH, C_CH, N_SP, PB, PB, SSTR, 0, 0, N_SP);
        softmax_kernel<<<dim3(N_SP, 2), 256, 0, stream>>>(S0, SSTR);
        // out[b][o][i] = sum_j hc[o][j] P[i][j] + f_c   (TM=64 for 512 blocks)
        gemm_bt<OUT_F32, 64><<<dim3(32, 8, 2), 256, 0, stream>>>(
            hc + g * 2 * PB, S0, (float*)d_out + g * 2 * PB, nullptr, nullptr, nullptr,
            f_c + g * 2 * PB,
            C_CH, N_SP, N_SP, N_SP, N_SP, N_SP, PB, SSTR, PB, PB, 0, 0);
    }
}

// Round 5
// 476.239 us; speedup vs baseline: 1.2271x; 1.2271x over previous
//
#include <hip/hip_runtime.h>

typedef unsigned short u16;
typedef __attribute__((ext_vector_type(8))) _Float16 f16x8;
typedef __attribute__((ext_vector_type(4))) float f32x4;

#define N_SP 4096
#define C_CH 512
#define B_SZ 4

struct PtrTab { u16* p[4]; };

__device__ __forceinline__ u16 f2h(float f) {
    union { _Float16 h; u16 u; } x; x.h = (_Float16)f; return x.u;
}
__device__ __forceinline__ float h2f(u16 u) {
    union { u16 u; _Float16 h; } x; x.u = u; return (float)x.h;
}
__device__ __forceinline__ void async_cp16(const void* g, void* l) {
    __builtin_amdgcn_global_load_lds((const __attribute__((address_space(1))) unsigned*)g,
                                     (__attribute__((address_space(3))) unsigned*)l, 16, 0, 0);
}
__device__ __forceinline__ float wave_reduce_sum(float v) {
    #pragma unroll
    for (int off = 32; off; off >>= 1) v += __shfl_xor(v, off, 64);
    return v;
}
__device__ __forceinline__ float wave_reduce_max(float v) {
    #pragma unroll
    for (int off = 32; off; off >>= 1) v = fmaxf(v, __shfl_xor(v, off, 64));
    return v;
}

// ---- transpose+cast raw x to fp16 [b][n][c], accumulate per-channel partial stats ----
__global__ __launch_bounds__(256) void transpose_cast_stats(
        const float* __restrict__ fc, const float* __restrict__ fs,
        u16* __restrict__ xc, u16* __restrict__ xs,
        float* __restrict__ part_s, float* __restrict__ part_ss) {
    __shared__ float tile[64][65];
    const int t = threadIdx.x;
    const int n0 = blockIdx.x * 64, c0 = blockIdx.y * 64;
    const int z = blockIdx.z;                      // (which<<2)|b
    const int b = z & 3, which = z >> 2;
    const float* src = which ? fs : fc;
    u16* dst = which ? xs : xc;
    const int r = t >> 4, q4 = (t & 15) * 4;
    #pragma unroll
    for (int it = 0; it < 4; ++it) {
        const int row = it * 16 + r;
        float4 v = *(const float4*)(src + ((size_t)b * C_CH + c0 + row) * N_SP + n0 + q4);
        tile[row][q4 + 0] = v.x; tile[row][q4 + 1] = v.y;
        tile[row][q4 + 2] = v.z; tile[row][q4 + 3] = v.w;
    }
    __syncthreads();
    {
        const int cr = t >> 2, q = t & 3;
        float s = 0.f, ss = 0.f;
        #pragma unroll
        for (int i = 0; i < 16; ++i) {
            float a = tile[cr][q * 16 + i];
            s += a; ss += a * a;
        }
        s += __shfl_xor(s, 1, 64);  s += __shfl_xor(s, 2, 64);
        ss += __shfl_xor(ss, 1, 64); ss += __shfl_xor(ss, 2, 64);
        if (q == 0) {
            atomicAdd(&part_s[z * 512 + c0 + cr], s);
            atomicAdd(&part_ss[z * 512 + c0 + cr], ss);
        }
    }
    #pragma unroll
    for (int it = 0; it < 4; ++it) {
        const int nrow = it * 16 + r;
        ushort4 h4;
        h4.x = f2h(tile[q4 + 0][nrow]);
        h4.y = f2h(tile[q4 + 1][nrow]);
        h4.z = f2h(tile[q4 + 2][nrow]);
        h4.w = f2h(tile[q4 + 3][nrow]);
        *(ushort4*)(dst + ((size_t)b * N_SP + n0 + nrow) * C_CH + c0 + q4) = h4;
    }
}

// ---- finalize stats: mu, rsqrt(var_unbiased+eps) ----
__global__ __launch_bounds__(256) void finalize_stats(const float* __restrict__ part_s,
                                                      const float* __restrict__ part_ss,
                                                      float* __restrict__ mu_a,
                                                      float* __restrict__ rs_a) {
    const int wb = blockIdx.x, t = threadIdx.x;
    #pragma unroll
    for (int h = 0; h < 2; ++h) {
        const int c = wb * 512 + h * 256 + t;
        const float S = part_s[c], SS = part_ss[c];
        const float mean = S * (1.f / N_SP);
        const float var = (SS - S * mean) * (1.f / (N_SP - 1));
        mu_a[c] = mean;
        rs_a[c] = rsqrtf(var + 1e-5f);
    }
}

// ---- weight cast (+transpose for z<3) fp32 -> fp16 ----
__global__ __launch_bounds__(256) void wtrans(const float* __restrict__ W0, const float* __restrict__ W1,
                                              const float* __restrict__ W2, const float* __restrict__ W3,
                                              u16* __restrict__ D0, u16* __restrict__ D1,
                                              u16* __restrict__ D2, u16* __restrict__ D3) {
    __shared__ float tile[64][65];
    const int t = threadIdx.x, z = blockIdx.z;
    const int n0 = blockIdx.x * 64, c0 = blockIdx.y * 64;
    const float* W = (z == 0) ? W0 : (z == 1) ? W1 : (z == 2) ? W2 : W3;
    u16* D = (z == 0) ? D0 : (z == 1) ? D1 : (z == 2) ? D2 : D3;
    const int r = t >> 4, q4 = (t & 15) * 4;
    #pragma unroll
    for (int it = 0; it < 4; ++it) {
        const int row = it * 16 + r;
        float4 v = *(const float4*)(W + (size_t)(c0 + row) * 512 + n0 + q4);
        if (z == 3) {
            ushort4 h4 = { f2h(v.x), f2h(v.y), f2h(v.z), f2h(v.w) };
            *(ushort4*)(D + (size_t)(c0 + row) * 512 + n0 + q4) = h4;
        } else {
            tile[row][q4 + 0] = v.x; tile[row][q4 + 1] = v.y;
            tile[row][q4 + 2] = v.z; tile[row][q4 + 3] = v.w;
        }
    }
    __syncthreads();
    if (z == 3) return;
    #pragma unroll
    for (int it = 0; it < 4; ++it) {
        const int nrow = it * 16 + r;
        ushort4 h4;
        h4.x = f2h(tile[q4 + 0][nrow]);
        h4.y = f2h(tile[q4 + 1][nrow]);
        h4.z = f2h(tile[q4 + 2][nrow]);
        h4.w = f2h(tile[q4 + 3][nrow]);
        *(ushort4*)(D + (size_t)(n0 + nrow) * 512 + c0 + q4) = h4;
    }
}

// ---- w_u[d] = sum_o b_c1[o] * W_s1[o][d] ----
__global__ __launch_bounds__(256) void wu_gemv(const float* __restrict__ Ws1,
                                               const float* __restrict__ bc1,
                                               float* __restrict__ w_u) {
    const int d = blockIdx.x * 256 + threadIdx.x;
    float acc = 0.f;
    for (int o = 0; o < 512; ++o) acc += bc1[o] * Ws1[(size_t)o * 512 + d];
    w_u[d] = acc;
}

// ---- bfold0[o] = sum_c W_csc[o][c] * b_s2[c] + b_csc[o] ----
__global__ __launch_bounds__(256) void bfold_gemv(const float* __restrict__ Wcsc,
                                                  const float* __restrict__ bs2,
                                                  const float* __restrict__ bcsc,
                                                  float* __restrict__ bfold0) {
    const int o = blockIdx.x * 4 + (threadIdx.x >> 6), l = threadIdx.x & 63;
    const float4 w0 = *(const float4*)(Wcsc + (size_t)o * 512 + l * 8);
    const float4 w1 = *(const float4*)(Wcsc + (size_t)o * 512 + l * 8 + 4);
    const float4 b0 = *(const float4*)(bs2 + l * 8);
    const float4 b1 = *(const float4*)(bs2 + l * 8 + 4);
    float acc = w0.x * b0.x + w0.y * b0.y + w0.z * b0.z + w0.w * b0.w
              + w1.x * b1.x + w1.y * b1.y + w1.z * b1.z + w1.w * b1.w;
    acc = wave_reduce_sum(acc);
    if (l == 0) bfold0[o] = acc + bcsc[o];
}

// ---- per-batch scaled weights: Wq_z[d][a] = WqT·rs_c[z][a]·rs_s[z][d]; Wf_z[o][k] = Wfold·rs_s[z][k] ----
__global__ __launch_bounds__(256) void make_scaled(const u16* __restrict__ WqT16,
                                                   const u16* __restrict__ Wf16,
                                                   const float* __restrict__ rs_a,
                                                   u16* __restrict__ Wq_z, u16* __restrict__ Wf_z) {
    const int y = blockIdx.y;
    const size_t e = ((size_t)blockIdx.x * 256 + threadIdx.x) * 8;   // < 1M
    const int z = (int)(e >> 18), rem = (int)(e & 262143);
    const int d = rem >> 9, a0 = rem & 511;
    u16 v[8];
    if (y == 0) {
        *(uint4*)v = *(const uint4*)(WqT16 + rem);
        const float rd = rs_a[(4 + z) * 512 + d];
        const float* rc = rs_a + z * 512 + a0;
        #pragma unroll
        for (int i = 0; i < 8; ++i) v[i] = f2h(h2f(v[i]) * rc[i] * rd);
        *(uint4*)(Wq_z + e) = *(const uint4*)v;
    } else {
        *(uint4*)v = *(const uint4*)(Wf16 + rem);
        const float* rk = rs_a + (4 + z) * 512 + a0;
        #pragma unroll
        for (int i = 0; i < 8; ++i) v[i] = f2h(h2f(v[i]) * rk[i]);
        *(uint4*)(Wf_z + e) = *(const uint4*)v;
    }
}

// ---- per-batch biases absorbing -mu terms ----
__global__ __launch_bounds__(256) void bias2_gemv(const u16* __restrict__ WqT16,
                                                  const u16* __restrict__ Wf16,
                                                  const float* __restrict__ mu_a,
                                                  const float* __restrict__ rs_a,
                                                  const float* __restrict__ bfold0,
                                                  float* __restrict__ bq, float* __restrict__ bh) {
    const int w = threadIdx.x >> 6, l = threadIdx.x & 63;
    const int oid = blockIdx.x * 4 + w;            // 0..4095
    const int kind = oid >> 11;                    // 0: bq, 1: bh
    const int z = (oid >> 9) & 3, d = oid & 511;
    const u16* row = (kind == 0 ? WqT16 : Wf16) + (size_t)d * 512;
    const int sb = (kind == 0 ? z : 4 + z) * 512;
    float acc = 0.f;
    #pragma unroll
    for (int i = 0; i < 8; ++i) {
        const int a = l * 8 + i;
        acc += h2f(row[a]) * mu_a[sb + a] * rs_a[sb + a];
    }
    acc = wave_reduce_sum(acc);
    if (l == 0) {
        if (kind == 0) bq[z * 512 + d] = -acc * rs_a[(4 + z) * 512 + d];
        else           bh[z * 512 + d] = bfold0[d] - acc;
    }
}

// ---- u[b][j] = sum_d (w_u[d]·rs_s[b][d]) * Xs_raw[b][j][d] ----
__global__ __launch_bounds__(256) void u_big(const u16* __restrict__ xs,
                                             const float* __restrict__ w_u,
                                             const float* __restrict__ rs_a,
                                             float* __restrict__ u) {
    const int b = blockIdx.y, w = threadIdx.x >> 6, l = threadIdx.x & 63;
    float4 u0 = *(const float4*)(w_u + l * 8);
    float4 u1 = *(const float4*)(w_u + l * 8 + 4);
    const float4 r0 = *(const float4*)(rs_a + (4 + b) * 512 + l * 8);
    const float4 r1 = *(const float4*)(rs_a + (4 + b) * 512 + l * 8 + 4);
    u0.x *= r0.x; u0.y *= r0.y; u0.z *= r0.z; u0.w *= r0.w;
    u1.x *= r1.x; u1.y *= r1.y; u1.z *= r1.z; u1.w *= r1.w;
    #pragma unroll
    for (int jj = 0; jj < 16; ++jj) {
        const int j = blockIdx.x * 64 + w * 16 + jj;
        const u16* row = xs + ((size_t)b * N_SP + j) * C_CH + l * 8;
        f16x8 x = *(const f16x8*)row;
        float acc = (float)x[0] * u0.x + (float)x[1] * u0.y + (float)x[2] * u0.z + (float)x[3] * u0.w
                  + (float)x[4] * u1.x + (float)x[5] * u1.y + (float)x[6] * u1.z + (float)x[7] * u1.w;
        acc = wave_reduce_sum(acc);
        if (l == 0) u[(size_t)b * N_SP + j] = acc;
    }
}

// ---------------- fp16 MFMA GEMM (bt form), BK=64, XOR-swizzled LDS ----------------
enum { OUT_F32 = 0, OUT_F16 = 1 };

template<int OUTMODE, bool TABB, bool TABD>
__global__ __launch_bounds__(256) void gemm_bt(
    const u16* __restrict__ A, const u16* __restrict__ B, PtrTab tab,
    float* __restrict__ Df, u16* __restrict__ Dh,
    const float* __restrict__ bias_m, const float* __restrict__ bias_n,
    const float* __restrict__ res,
    int M, int N, int K, int lda, int ldb, int ldd,
    size_t sA, size_t sB, size_t sD, size_t sR, int sBm, int sBn)
{
    constexpr int TM = 128, TN = 128, BK = 64;
    __shared__ u16 smem[(TM + TN) * BK];          // 32 KB
    u16* As = smem;
    u16* Bs = smem + TM * BK;

    const int t = threadIdx.x;
    const int l = t & 63, w = t >> 6;
    const int m0 = blockIdx.y * TM, n0 = blockIdx.x * TN;
    const size_t zb = blockIdx.z;
    const u16* pA = A + zb * sA + (size_t)m0 * lda;
    const u16* pB = (TABB ? tab.p[zb] : B + zb * sB) + (size_t)n0 * ldb;

    const int wr = (w & 1) * 64, wc = (w >> 1) * 64;

    f32x4 acc[4][4] = {};

    for (int k0 = 0; k0 < K; k0 += BK) {
        #pragma unroll
        for (int it = 0; it < 4; ++it) {
            const int L = it * 256 + t;
            const int row = L >> 3, c = L & 7;
            const int sc = (c ^ (row & 7)) * 8;    // source-chunk XOR swizzle
            async_cp16(pA + (size_t)row * lda + k0 + sc, As + L * 8);
        }
        #pragma unroll
        for (int it = 0; it < 4; ++it) {
            const int L = it * 256 + t;
            const int row = L >> 3, c = L & 7;
            const int sc = (c ^ (row & 7)) * 8;
            async_cp16(pB + (size_t)row * ldb + k0 + sc, Bs + L * 8);
        }
        __syncthreads();
        #pragma unroll
        for (int kk = 0; kk < 2; ++kk) {
            const int cc = (l >> 4) + kk * 4;
            f16x8 af[4], bf[4];
            #pragma unroll
            for (int i = 0; i < 4; ++i) {
                const int row = wr + i * 16 + (l & 15);
                af[i] = *(const f16x8*)(As + row * BK + ((cc ^ (row & 7)) * 8));
            }
            #pragma unroll
            for (int j = 0; j < 4; ++j) {
                const int row = wc + j * 16 + (l & 15);
                bf[j] = *(const f16x8*)(Bs + row * BK + ((cc ^ (row & 7)) * 8));
            }
            #pragma unroll
            for (int i = 0; i < 4; ++i)
                #pragma unroll
                for (int j = 0; j < 4; ++j)
                    acc[i][j] = __builtin_amdgcn_mfma_f32_16x16x32_f16(af[i], bf[j], acc[i][j], 0, 0, 0);
        }
        __syncthreads();
    }

    const int em = m0 + wr + (l >> 4) * 4;
    const int en = n0 + wc + (l & 15);
    u16* pDh = (OUTMODE == OUT_F16) ? (TABD ? tab.p[zb] : Dh + zb * sD) : nullptr;
    float* pDf = (OUTMODE == OUT_F32) ? (Df + zb * sD) : nullptr;
    #pragma unroll
    for (int i = 0; i < 4; ++i) {
        #pragma unroll
        for (int j = 0; j < 4; ++j) {
            const int nn = en + j * 16;
            const float bn = bias_n ? bias_n[(size_t)sBn * zb + nn] : 0.f;
            #pragma unroll
            for (int r = 0; r < 4; ++r) {
                const int mm = em + i * 16 + r;
                float v = acc[i][j][r] + bn;
                if (bias_m) v += bias_m[(size_t)sBm * zb + mm];
                const size_t off = (size_t)mm * ldd + nn;
                if (OUTMODE == OUT_F32) {
                    if (res) v += res[zb * sR + off];
                    pDf[off] = v;
                } else {
                    pDh[off] = f2h(v);
                }
            }
        }
    }
}

// ---------------- softmax row-wise, fp16 in-place ----------------
__global__ __launch_bounds__(256) void softmax_kernel(PtrTab tab) {
    u16* row = tab.p[blockIdx.y] + (size_t)blockIdx.x * N_SP;
    const int t = threadIdx.x;
    u16 raw[16];
    *(uint4*)(raw + 0) = *(const uint4*)(row + t * 16);
    *(uint4*)(raw + 8) = *(const uint4*)(row + t * 16 + 8);
    float v[16];
    float mx = -1e30f;
    #pragma unroll
    for (int i = 0; i < 16; ++i) { v[i] = h2f(raw[i]); mx = fmaxf(mx, v[i]); }
    mx = wave_reduce_max(mx);
    __shared__ float red[4];
    const int wave = t >> 6;
    if ((t & 63) == 0) red[wave] = mx;
    __syncthreads();
    mx = fmaxf(fmaxf(red[0], red[1]), fmaxf(red[2], red[3]));
    float sum = 0.f;
    #pragma unroll
    for (int i = 0; i < 16; ++i) { v[i] = __expf(v[i] - mx); sum += v[i]; }
    sum = wave_reduce_sum(sum);
    __syncthreads();
    if ((t & 63) == 0) red[wave] = sum;
    __syncthreads();
    const float inv = 1.f / (red[0] + red[1] + red[2] + red[3]);
    #pragma unroll
    for (int i = 0; i < 16; ++i) raw[i] = f2h(v[i] * inv);
    *(uint4*)(row + t * 16)     = *(const uint4*)(raw + 0);
    *(uint4*)(row + t * 16 + 8) = *(const uint4*)(raw + 8);
}

extern "C" void kernel_launch(void* const* d_in, const int* in_sizes, int n_in,
                              void* d_out, int out_size, void* d_ws, size_t ws_size,
                              hipStream_t stream) {
    const float* f_c   = (const float*)d_in[0];
    const float* f_s   = (const float*)d_in[1];
    const float* W_c1  = (const float*)d_in[2];
    const float* b_c1  = (const float*)d_in[3];
    const float* W_s1  = (const float*)d_in[4];
    const float* b_s1  = (const float*)d_in[5]; (void)b_s1;   // softmax-invariant, dropped
    const float* W_s2  = (const float*)d_in[6];
    const float* b_s2  = (const float*)d_in[7];
    const float* W_csc = (const float*)d_in[8];
    const float* b_csc = (const float*)d_in[9];

    const size_t PB = (size_t)N_SP * C_CH;      // 2M elems per batch plane
    const size_t M1 = 1024 * 1024;

    u16* ws   = (u16*)d_ws;
    u16* Xs   = ws;                 // raw fp16 [b][j][c]   0..8M
    u16* q_   = ws + 8 * M1;        // q'[b][i][d]          8..16M
    u16* hc   = ws + 16 * M1;       // hc[b][o][j]          16..24M
    u16* Xc   = ws + 24 * M1;       // raw fp16             24..32M (dead after q'-conv)
    u16* S3   = ws + 24 * M1;       // 32MB S batch 3 aliases Xc.. (24..40M)
    u16* S0   = ws + 40 * M1;
    u16* S1   = ws + 56 * M1;
    u16* S2   = ws + 72 * M1;
    u16* Wc1T = ws + 88 * M1;
    u16* Ws1T = Wc1T + 262144;
    u16* Ws2T = Ws1T + 262144;
    u16* Wcs16= Ws2T + 262144;
    u16* WqT16= Wcs16 + 262144;
    u16* Wf16 = WqT16 + 262144;
    u16* Wq_z = Wf16 + 262144;      // 4 x 256K
    u16* Wf_z = Wq_z + 1048576;     // 4 x 256K
    float* f32b = (float*)(ws + 92 * M1);
    float* part_s  = f32b;          // 4096
    float* part_ss = f32b + 4096;
    float* mu_a    = f32b + 8192;
    float* rs_a    = f32b + 12288;
    float* w_u     = f32b + 16384;  // 512
    float* bfold0  = f32b + 16896;  // 512
    float* bq      = f32b + 17408;  // 2048
    float* bh      = f32b + 19456;  // 2048
    float* u_      = f32b + 21504;  // 4*4096

    PtrTab Stab; Stab.p[0] = S0; Stab.p[1] = S1; Stab.p[2] = S2; Stab.p[3] = S3;
    PtrTab tab0 = Stab;

    hipMemsetAsync(part_s, 0, 2 * 4096 * sizeof(float), stream);

    transpose_cast_stats<<<dim3(64, 8, 8), 256, 0, stream>>>(f_c, f_s, Xc, Xs, part_s, part_ss);
    finalize_stats<<<8, 256, 0, stream>>>(part_s, part_ss, mu_a, rs_a);
    wtrans<<<dim3(8, 8, 4), 256, 0, stream>>>(W_c1, W_s1, W_s2, W_csc, Wc1T, Ws1T, Ws2T, Wcs16);
    wu_gemv<<<2, 256, 0, stream>>>(W_s1, b_c1, w_u);
    bfold_gemv<<<128, 256, 0, stream>>>(W_csc, b_s2, b_csc, bfold0);

    // WqT[d][a] = sum_o W_s1[o][d] W_c1[o][a]
    gemm_bt<OUT_F16, false, false><<<dim3(4, 4, 1), 256, 0, stream>>>(
        Ws1T, Wc1T, tab0, nullptr, WqT16, nullptr, nullptr, nullptr,
        512, 512, 512, 512, 512, 512, 0, 0, 0, 0, 0, 0);
    // Wfold[o][k] = sum_c W_csc[o][c] W_s2[c][k]
    gemm_bt<OUT_F16, false, false><<<dim3(4, 4, 1), 256, 0, stream>>>(
        Wcs16, Ws2T, tab0, nullptr, Wf16, nullptr, nullptr, nullptr,
        512, 512, 512, 512, 512, 512, 0, 0, 0, 0, 0, 0);

    make_scaled<<<dim3(512, 2), 256, 0, stream>>>(WqT16, Wf16, rs_a, Wq_z, Wf_z);
    bias2_gemv<<<1024, 256, 0, stream>>>(WqT16, Wf16, mu_a, rs_a, bfold0, bq, bh);

    // q'[b][i][d] = sum_a Xc_raw[b][i][a] Wq_z[b][d][a] + bq[b][d]
    gemm_bt<OUT_F16, false, false><<<dim3(4, 32, B_SZ), 256, 0, stream>>>(
        Xc, Wq_z, tab0, nullptr, q_, nullptr, bq, nullptr,
        N_SP, C_CH, C_CH, C_CH, C_CH, C_CH, PB, 262144, PB, 0, 0, 512);
    // hc[b][o][j] = sum_k Wf_z[b][o][k] Xs_raw[b][j][k] + bh[b][o]
    gemm_bt<OUT_F16, false, false><<<dim3(32, 4, B_SZ), 256, 0, stream>>>(
        Wf_z, Xs, tab0, nullptr, hc, bh, nullptr, nullptr,
        C_CH, N_SP, C_CH, C_CH, C_CH, N_SP, 262144, PB, PB, 0, 512, 0);
    // u[b][j]
    u_big<<<dim3(64, B_SZ), 256, 0, stream>>>(Xs, w_u, rs_a, u_);

    // S_b[i][j] = sum_d q'[i][d] Xs_raw[j][d] + u[b][j]   (fp16 out into per-batch S)
    gemm_bt<OUT_F16, false, true><<<dim3(32, 32, B_SZ), 256, 0, stream>>>(
        q_, Xs, Stab, nullptr, nullptr, nullptr, u_, nullptr,
        N_SP, N_SP, C_CH, C_CH, C_CH, N_SP, PB, PB, 0, 0, 0, N_SP);

    softmax_kernel<<<dim3(N_SP, B_SZ), 256, 0, stream>>>(Stab);

    // out[b][o][i] = sum_j hc[o][j] P[i][j] + f_c
    gemm_bt<OUT_F32, true, false><<<dim3(32, 4, B_SZ), 256, 0, stream>>>(
        hc, nullptr, Stab, (float*)d_out, nullptr, nullptr, nullptr, f_c,
        C_CH, N_SP, N_SP, N_SP, N_SP, N_SP, PB, 0, PB, PB, 0, 0);
}

// Round 6
// 450.818 us; speedup vs baseline: 1.2963x; 1.0564x over previous
//
#include <hip/hip_runtime.h>

typedef unsigned short u16;
typedef __attribute__((ext_vector_type(8))) _Float16 f16x8;
typedef __attribute__((ext_vector_type(16))) float f32x16;

#define N_SP 4096
#define C_CH 512
#define B_SZ 4

struct PtrTab { u16* p[4]; };

__device__ __forceinline__ u16 f2h(float f) {
    union { _Float16 h; u16 u; } x; x.h = (_Float16)f; return x.u;
}
__device__ __forceinline__ float h2f(u16 u) {
    union { u16 u; _Float16 h; } x; x.u = u; return (float)x.h;
}
__device__ __forceinline__ void async_cp16(const void* g, void* l) {
    __builtin_amdgcn_global_load_lds((const __attribute__((address_space(1))) unsigned*)g,
                                     (__attribute__((address_space(3))) unsigned*)l, 16, 0, 0);
}
__device__ __forceinline__ float wave_reduce_sum(float v) {
    #pragma unroll
    for (int off = 32; off; off >>= 1) v += __shfl_xor(v, off, 64);
    return v;
}
__device__ __forceinline__ float wave_reduce_max(float v) {
    #pragma unroll
    for (int off = 32; off; off >>= 1) v = fmaxf(v, __shfl_xor(v, off, 64));
    return v;
}

// ---- transpose+cast raw x to fp16 [b][n][c], accumulate per-channel partial stats ----
__global__ __launch_bounds__(256) void transpose_cast_stats(
        const float* __restrict__ fc, const float* __restrict__ fs,
        u16* __restrict__ xc, u16* __restrict__ xs,
        float* __restrict__ part_s, float* __restrict__ part_ss) {
    __shared__ float tile[64][65];
    const int t = threadIdx.x;
    const int n0 = blockIdx.x * 64, c0 = blockIdx.y * 64;
    const int z = blockIdx.z;                      // (which<<2)|b
    const int b = z & 3, which = z >> 2;
    const float* src = which ? fs : fc;
    u16* dst = which ? xs : xc;
    const int r = t >> 4, q4 = (t & 15) * 4;
    #pragma unroll
    for (int it = 0; it < 4; ++it) {
        const int row = it * 16 + r;
        float4 v = *(const float4*)(src + ((size_t)b * C_CH + c0 + row) * N_SP + n0 + q4);
        tile[row][q4 + 0] = v.x; tile[row][q4 + 1] = v.y;
        tile[row][q4 + 2] = v.z; tile[row][q4 + 3] = v.w;
    }
    __syncthreads();
    {
        const int cr = t >> 2, q = t & 3;
        float s = 0.f, ss = 0.f;
        #pragma unroll
        for (int i = 0; i < 16; ++i) {
            float a = tile[cr][q * 16 + i];
            s += a; ss += a * a;
        }
        s += __shfl_xor(s, 1, 64);  s += __shfl_xor(s, 2, 64);
        ss += __shfl_xor(ss, 1, 64); ss += __shfl_xor(ss, 2, 64);
        if (q == 0) {
            atomicAdd(&part_s[z * 512 + c0 + cr], s);
            atomicAdd(&part_ss[z * 512 + c0 + cr], ss);
        }
    }
    #pragma unroll
    for (int it = 0; it < 4; ++it) {
        const int nrow = it * 16 + r;
        ushort4 h4;
        h4.x = f2h(tile[q4 + 0][nrow]);
        h4.y = f2h(tile[q4 + 1][nrow]);
        h4.z = f2h(tile[q4 + 2][nrow]);
        h4.w = f2h(tile[q4 + 3][nrow]);
        *(ushort4*)(dst + ((size_t)b * N_SP + n0 + nrow) * C_CH + c0 + q4) = h4;
    }
}

// ---- prep1: weight transpose/cast + finalize stats + wu gemv + bfold gemv ----
// Wbase slots (each 262144 u16): 0 Ws1T, 1 Wcs16, 2 Wc1T, 3 Ws2T, 4 WqT16, 5 Wf16
__global__ __launch_bounds__(256) void prep1(
        const float* __restrict__ W_c1, const float* __restrict__ W_s1,
        const float* __restrict__ W_s2, const float* __restrict__ W_csc,
        const float* __restrict__ b_c1, const float* __restrict__ b_s2,
        const float* __restrict__ b_csc,
        u16* __restrict__ Wbase,
        const float* __restrict__ part_s, const float* __restrict__ part_ss,
        float* __restrict__ mu_a, float* __restrict__ rs_a,
        float* __restrict__ w_u, float* __restrict__ bfold0) {
    __shared__ float tile[64][65];
    const int t = threadIdx.x, z = blockIdx.z;
    if (z < 4) {
        const int n0 = blockIdx.x * 64, c0 = blockIdx.y * 64;
        const float* W = (z == 0) ? W_c1 : (z == 1) ? W_s1 : (z == 2) ? W_s2 : W_csc;
        u16* D = Wbase + ((z == 0) ? 2 : (z == 1) ? 0 : (z == 2) ? 3 : 1) * 262144;
        const int r = t >> 4, q4 = (t & 15) * 4;
        #pragma unroll
        for (int it = 0; it < 4; ++it) {
            const int row = it * 16 + r;
            float4 v = *(const float4*)(W + (size_t)(c0 + row) * 512 + n0 + q4);
            if (z == 3) {
                ushort4 h4 = { f2h(v.x), f2h(v.y), f2h(v.z), f2h(v.w) };
                *(ushort4*)(D + (size_t)(c0 + row) * 512 + n0 + q4) = h4;
            } else {
                tile[row][q4 + 0] = v.x; tile[row][q4 + 1] = v.y;
                tile[row][q4 + 2] = v.z; tile[row][q4 + 3] = v.w;
            }
        }
        __syncthreads();
        if (z == 3) return;
        #pragma unroll
        for (int it = 0; it < 4; ++it) {
            const int nrow = it * 16 + r;
            ushort4 h4;
            h4.x = f2h(tile[q4 + 0][nrow]);
            h4.y = f2h(tile[q4 + 1][nrow]);
            h4.z = f2h(tile[q4 + 2][nrow]);
            h4.w = f2h(tile[q4 + 3][nrow]);
            *(ushort4*)(D + (size_t)(n0 + nrow) * 512 + c0 + q4) = h4;
        }
        return;
    }
    const int flat = blockIdx.y * 8 + blockIdx.x;
    if (flat < 8) {               // finalize stats
        #pragma unroll
        for (int h = 0; h < 2; ++h) {
            const int c = flat * 512 + h * 256 + t;
            const float S = part_s[c], SS = part_ss[c];
            const float mean = S * (1.f / N_SP);
            const float var = (SS - S * mean) * (1.f / (N_SP - 1));
            mu_a[c] = mean;
            rs_a[c] = rsqrtf(var + 1e-5f);
        }
    } else if (flat < 10) {       // w_u[d] = sum_o b_c1[o] W_s1[o][d]
        const int d = (flat - 8) * 256 + t;
        float acc = 0.f;
        for (int o = 0; o < 512; ++o) acc += b_c1[o] * W_s1[(size_t)o * 512 + d];
        w_u[d] = acc;
    } else if (flat < 42) {       // bfold0[o] = sum_c W_csc[o][c] b_s2[c] + b_csc[o]
        const int w4 = t >> 6, l = t & 63;
        #pragma unroll
        for (int q = 0; q < 4; ++q) {
            const int o = (flat - 10) * 16 + w4 * 4 + q;
            const float4 w0 = *(const float4*)(W_csc + (size_t)o * 512 + l * 8);
            const float4 w1 = *(const float4*)(W_csc + (size_t)o * 512 + l * 8 + 4);
            const float4 b0 = *(const float4*)(b_s2 + l * 8);
            const float4 b1 = *(const float4*)(b_s2 + l * 8 + 4);
            float acc = w0.x * b0.x + w0.y * b0.y + w0.z * b0.z + w0.w * b0.w
                      + w1.x * b1.x + w1.y * b1.y + w1.z * b1.z + w1.w * b1.w;
            acc = wave_reduce_sum(acc);
            if (l == 0) bfold0[o] = acc + b_csc[o];
        }
    }
}

// ---- prep2: make_scaled + bias2 + u_big, one launch (grid 2304) ----
__global__ __launch_bounds__(256) void prep2(
        const u16* __restrict__ WqT16, const u16* __restrict__ Wf16,
        const u16* __restrict__ xs,
        const float* __restrict__ mu_a, const float* __restrict__ rs_a,
        const float* __restrict__ bfold0, const float* __restrict__ w_u,
        u16* __restrict__ Wq_z, u16* __restrict__ Wf_z,
        float* __restrict__ bq, float* __restrict__ bh, float* __restrict__ u_) {
    const int id = blockIdx.x, t = threadIdx.x;
    if (id < 1024) {              // make_scaled
        const int y = id >> 9;
        const size_t e = ((size_t)(id & 511) * 256 + t) * 8;
        const int z = (int)(e >> 18), rem = (int)(e & 262143);
        const int d = rem >> 9, a0 = rem & 511;
        u16 v[8];
        if (y == 0) {
            *(uint4*)v = *(const uint4*)(WqT16 + rem);
            const float rd = rs_a[(4 + z) * 512 + d];
            const float* rc = rs_a + z * 512 + a0;
            #pragma unroll
            for (int i = 0; i < 8; ++i) v[i] = f2h(h2f(v[i]) * rc[i] * rd);
            *(uint4*)(Wq_z + e) = *(const uint4*)v;
        } else {
            *(uint4*)v = *(const uint4*)(Wf16 + rem);
            const float* rk = rs_a + (4 + z) * 512 + a0;
            #pragma unroll
            for (int i = 0; i < 8; ++i) v[i] = f2h(h2f(v[i]) * rk[i]);
            *(uint4*)(Wf_z + e) = *(const uint4*)v;
        }
    } else if (id < 2048) {       // bias2
        const int w = t >> 6, l = t & 63;
        const int oid = (id - 1024) * 4 + w;
        const int kind = oid >> 11;
        const int z = (oid >> 9) & 3, d = oid & 511;
        const u16* row = (kind == 0 ? WqT16 : Wf16) + (size_t)d * 512;
        const int sb = (kind == 0 ? z : 4 + z) * 512;
        float acc = 0.f;
        #pragma unroll
        for (int i = 0; i < 8; ++i) {
            const int a = l * 8 + i;
            acc += h2f(row[a]) * mu_a[sb + a] * rs_a[sb + a];
        }
        acc = wave_reduce_sum(acc);
        if (l == 0) {
            if (kind == 0) bq[z * 512 + d] = -acc * rs_a[(4 + z) * 512 + d];
            else           bh[z * 512 + d] = bfold0[d] - acc;
        }
    } else {                      // u_big
        const int id2 = id - 2048;                 // 0..255
        const int b = id2 >> 6, xblk = id2 & 63;
        const int w = t >> 6, l = t & 63;
        float4 u0 = *(const float4*)(w_u + l * 8);
        float4 u1 = *(const float4*)(w_u + l * 8 + 4);
        const float4 r0 = *(const float4*)(rs_a + (4 + b) * 512 + l * 8);
        const float4 r1 = *(const float4*)(rs_a + (4 + b) * 512 + l * 8 + 4);
        u0.x *= r0.x; u0.y *= r0.y; u0.z *= r0.z; u0.w *= r0.w;
        u1.x *= r1.x; u1.y *= r1.y; u1.z *= r1.z; u1.w *= r1.w;
        #pragma unroll
        for (int jj = 0; jj < 16; ++jj) {
            const int j = xblk * 64 + w * 16 + jj;
            const u16* row = xs + ((size_t)b * N_SP + j) * C_CH + l * 8;
            f16x8 x = *(const f16x8*)row;
            float acc = (float)x[0] * u0.x + (float)x[1] * u0.y + (float)x[2] * u0.z + (float)x[3] * u0.w
                      + (float)x[4] * u1.x + (float)x[5] * u1.y + (float)x[6] * u1.z + (float)x[7] * u1.w;
            acc = wave_reduce_sum(acc);
            if (l == 0) u_[(size_t)b * N_SP + j] = acc;
        }
    }
}

// ---------------- fp16 MFMA GEMM (bt form), 32x32x16, BK=64, XOR-swizzled LDS ----------------
enum { OUT_F32 = 0, OUT_F16 = 1 };

template<int OUTMODE, bool TABB, bool TABD>
__global__ __launch_bounds__(256) void gemm_bt(
    const u16* __restrict__ A, const u16* __restrict__ B, PtrTab tab,
    float* __restrict__ Df, u16* __restrict__ Dh,
    const float* __restrict__ bias_m, const float* __restrict__ bias_n,
    const float* __restrict__ res,
    int M, int N, int K, int lda, int ldb, int ldd,
    size_t sA, size_t sB, size_t sD, size_t sR, int sBm, int sBn)
{
    constexpr int TM = 128, TN = 128, BK = 64;
    __shared__ u16 smem[(TM + TN) * BK];          // 32 KB
    u16* As = smem;
    u16* Bs = smem + TM * BK;

    const int t = threadIdx.x;
    const int l = t & 63, w = t >> 6;
    const int m0 = blockIdx.y * TM, n0 = blockIdx.x * TN;
    const size_t zb = blockIdx.z;
    const u16* pA = A + zb * sA + (size_t)m0 * lda;
    const u16* pB = (TABB ? tab.p[zb] : B + zb * sB) + (size_t)n0 * ldb;

    const int wr = (w & 1) * 64, wc = (w >> 1) * 64;

    f32x16 acc[2][2] = {};

    for (int k0 = 0; k0 < K; k0 += BK) {
        #pragma unroll
        for (int it = 0; it < 4; ++it) {
            const int L = it * 256 + t;
            const int row = L >> 3, c = L & 7;
            const int sc = (c ^ (row & 7)) * 8;    // source-chunk XOR swizzle
            async_cp16(pA + (size_t)row * lda + k0 + sc, As + L * 8);
        }
        #pragma unroll
        for (int it = 0; it < 4; ++it) {
            const int L = it * 256 + t;
            const int row = L >> 3, c = L & 7;
            const int sc = (c ^ (row & 7)) * 8;
            async_cp16(pB + (size_t)row * ldb + k0 + sc, Bs + L * 8);
        }
        __syncthreads();
        #pragma unroll
        for (int kk = 0; kk < 4; ++kk) {
            f16x8 af[2], bf[2];
            #pragma unroll
            for (int i = 0; i < 2; ++i) {
                const int row = wr + i * 32 + (l & 31);
                const int ch = ((kk * 2 + (l >> 5)) ^ (row & 7)) * 8;
                af[i] = *(const f16x8*)(As + row * BK + ch);
            }
            #pragma unroll
            for (int j = 0; j < 2; ++j) {
                const int row = wc + j * 32 + (l & 31);
                const int ch = ((kk * 2 + (l >> 5)) ^ (row & 7)) * 8;
                bf[j] = *(const f16x8*)(Bs + row * BK + ch);
            }
            #pragma unroll
            for (int i = 0; i < 2; ++i)
                #pragma unroll
                for (int j = 0; j < 2; ++j)
                    acc[i][j] = __builtin_amdgcn_mfma_f32_32x32x16_f16(af[i], bf[j], acc[i][j], 0, 0, 0);
        }
        __syncthreads();
    }

    // C/D layout (32x32): col = lane&31, row = (reg&3) + 8*(reg>>2) + 4*(lane>>5)
    const int cl = l & 31, rh = (l >> 5) * 4;
    u16* pDh = (OUTMODE == OUT_F16) ? (TABD ? tab.p[zb] : Dh + zb * sD) : nullptr;
    float* pDf = (OUTMODE == OUT_F32) ? (Df + zb * sD) : nullptr;
    #pragma unroll
    for (int i = 0; i < 2; ++i) {
        #pragma unroll
        for (int j = 0; j < 2; ++j) {
            const int nn = n0 + wc + j * 32 + cl;
            const float bn = bias_n ? bias_n[(size_t)sBn * zb + nn] : 0.f;
            #pragma unroll
            for (int reg = 0; reg < 16; ++reg) {
                const int ml = (reg & 3) + 8 * (reg >> 2) + rh;
                const int mm = m0 + wr + i * 32 + ml;
                float v = acc[i][j][reg] + bn;
                if (bias_m) v += bias_m[(size_t)sBm * zb + mm];
                const size_t off = (size_t)mm * ldd + nn;
                if (OUTMODE == OUT_F32) {
                    if (res) v += res[zb * sR + off];
                    pDf[off] = v;
                } else {
                    pDh[off] = f2h(v);
                }
            }
        }
    }
}

// ---------------- softmax row-wise, fp16 in-place ----------------
__global__ __launch_bounds__(256) void softmax_kernel(PtrTab tab) {
    u16* row = tab.p[blockIdx.y] + (size_t)blockIdx.x * N_SP;
    const int t = threadIdx.x;
    u16 raw[16];
    *(uint4*)(raw + 0) = *(const uint4*)(row + t * 16);
    *(uint4*)(raw + 8) = *(const uint4*)(row + t * 16 + 8);
    float v[16];
    float mx = -1e30f;
    #pragma unroll
    for (int i = 0; i < 16; ++i) { v[i] = h2f(raw[i]); mx = fmaxf(mx, v[i]); }
    mx = wave_reduce_max(mx);
    __shared__ float red[4];
    const int wave = t >> 6;
    if ((t & 63) == 0) red[wave] = mx;
    __syncthreads();
    mx = fmaxf(fmaxf(red[0], red[1]), fmaxf(red[2], red[3]));
    float sum = 0.f;
    #pragma unroll
    for (int i = 0; i < 16; ++i) { v[i] = __expf(v[i] - mx); sum += v[i]; }
    sum = wave_reduce_sum(sum);
    __syncthreads();
    if ((t & 63) == 0) red[wave] = sum;
    __syncthreads();
    const float inv = 1.f / (red[0] + red[1] + red[2] + red[3]);
    #pragma unroll
    for (int i = 0; i < 16; ++i) raw[i] = f2h(v[i] * inv);
    *(uint4*)(row + t * 16)     = *(const uint4*)(raw + 0);
    *(uint4*)(row + t * 16 + 8) = *(const uint4*)(raw + 8);
}

extern "C" void kernel_launch(void* const* d_in, const int* in_sizes, int n_in,
                              void* d_out, int out_size, void* d_ws, size_t ws_size,
                              hipStream_t stream) {
    const float* f_c   = (const float*)d_in[0];
    const float* f_s   = (const float*)d_in[1];
    const float* W_c1  = (const float*)d_in[2];
    const float* b_c1  = (const float*)d_in[3];
    const float* W_s1  = (const float*)d_in[4];
    const float* b_s1  = (const float*)d_in[5]; (void)b_s1;   // softmax-invariant, dropped
    const float* W_s2  = (const float*)d_in[6];
    const float* b_s2  = (const float*)d_in[7];
    const float* W_csc = (const float*)d_in[8];
    const float* b_csc = (const float*)d_in[9];

    const size_t PB = (size_t)N_SP * C_CH;      // 2M elems per batch plane
    const size_t M1 = 1024 * 1024;

    u16* ws   = (u16*)d_ws;
    u16* Xs   = ws;                 // raw fp16 [b][j][c]   0..8M
    u16* q_   = ws + 8 * M1;        // q'[b][i][d]          8..16M
    u16* hc   = ws + 16 * M1;       // hc[b][o][j]          16..24M
    u16* Xc   = ws + 24 * M1;       // raw fp16 (dead after q'-conv; S3 aliases)
    u16* S3   = ws + 24 * M1;
    u16* S0   = ws + 40 * M1;
    u16* S1   = ws + 56 * M1;
    u16* S2   = ws + 72 * M1;
    u16* Wbase= ws + 88 * M1;       // 6 x 262144: Ws1T, Wcs16, Wc1T, Ws2T, WqT16, Wf16
    u16* WqT16= Wbase + 4 * 262144;
    u16* Wf16 = Wbase + 5 * 262144;
    u16* Wq_z = Wbase + 6 * 262144; // 4 x 256K
    u16* Wf_z = Wq_z + 1048576;     // 4 x 256K
    float* f32b = (float*)(ws + 92 * M1);
    float* part_s  = f32b;          // 4096
    float* part_ss = f32b + 4096;
    float* mu_a    = f32b + 8192;
    float* rs_a    = f32b + 12288;
    float* w_u     = f32b + 16384;  // 512
    float* bfold0  = f32b + 16896;  // 512
    float* bq      = f32b + 17408;  // 2048
    float* bh      = f32b + 19456;  // 2048
    float* u_      = f32b + 21504;  // 4*4096

    PtrTab Stab; Stab.p[0] = S0; Stab.p[1] = S1; Stab.p[2] = S2; Stab.p[3] = S3;
    PtrTab tab0 = Stab;

    hipMemsetAsync(part_s, 0, 2 * 4096 * sizeof(float), stream);

    transpose_cast_stats<<<dim3(64, 8, 8), 256, 0, stream>>>(f_c, f_s, Xc, Xs, part_s, part_ss);

    // weight transforms + stats finalize + small gemvs, one launch
    prep1<<<dim3(8, 8, 5), 256, 0, stream>>>(W_c1, W_s1, W_s2, W_csc, b_c1, b_s2, b_csc,
                                             Wbase, part_s, part_ss, mu_a, rs_a, w_u, bfold0);

    // WqT[d][a] = sum_o Ws1T[d][o] Wc1T[a][o]; Wfold[o][k] = sum_c Wcs16[o][c] Ws2T[k][c]
    gemm_bt<OUT_F16, false, false><<<dim3(4, 4, 2), 256, 0, stream>>>(
        Wbase, Wbase + 2 * 262144, tab0, nullptr, WqT16, nullptr, nullptr, nullptr,
        512, 512, 512, 512, 512, 512, 262144, 262144, 262144, 0, 0, 0);

    // per-batch scaled weights + folded biases + u vector, one launch
    prep2<<<2304, 256, 0, stream>>>(WqT16, Wf16, Xs, mu_a, rs_a, bfold0, w_u,
                                    Wq_z, Wf_z, bq, bh, u_);

    // q'[b][i][d] = sum_a Xc_raw[b][i][a] Wq_z[b][d][a] + bq[b][d]
    gemm_bt<OUT_F16, false, false><<<dim3(4, 32, B_SZ), 256, 0, stream>>>(
        Xc, Wq_z, tab0, nullptr, q_, nullptr, bq, nullptr,
        N_SP, C_CH, C_CH, C_CH, C_CH, C_CH, PB, 262144, PB, 0, 0, 512);
    // hc[b][o][j] = sum_k Wf_z[b][o][k] Xs_raw[b][j][k] + bh[b][o]
    gemm_bt<OUT_F16, false, false><<<dim3(32, 4, B_SZ), 256, 0, stream>>>(
        Wf_z, Xs, tab0, nullptr, hc, bh, nullptr, nullptr,
        C_CH, N_SP, C_CH, C_CH, C_CH, N_SP, 262144, PB, PB, 0, 512, 0);

    // S_b[i][j] = sum_d q'[i][d] Xs_raw[j][d] + u[b][j]
    gemm_bt<OUT_F16, false, true><<<dim3(32, 32, B_SZ), 256, 0, stream>>>(
        q_, Xs, Stab, nullptr, nullptr, nullptr, u_, nullptr,
        N_SP, N_SP, C_CH, C_CH, C_CH, N_SP, PB, PB, 0, 0, 0, N_SP);

    softmax_kernel<<<dim3(N_SP, B_SZ), 256, 0, stream>>>(Stab);

    // out[b][o][i] = sum_j hc[o][j] P[i][j] + f_c
    gemm_bt<OUT_F32, true, false><<<dim3(32, 4, B_SZ), 256, 0, stream>>>(
        hc, nullptr, Stab, (float*)d_out, nullptr, nullptr, nullptr, f_c,
        C_CH, N_SP, N_SP, N_SP, N_SP, N_SP, PB, 0, PB, PB, 0, 0);
}